// Round 1
// 71.844 us; speedup vs baseline: 1.0040x; 1.0040x over previous
//
#include <hip/hip_runtime.h>

// Cubic B-spline eval on uniform extended grid.
// KNOTS=64, DEGREE=3 -> h = 2/63, extended grid len 70, coeffs used: 66.
// For x in [-1,1): j = floor((x+1)*31.5) in [0,62], t = frac; output =
//   w0(t)*c[j] + w1(t)*c[j+1] + w2(t)*c[j+2] + w3(t)*c[j+3]
//
// v2 changes vs v1 (71.7 us session best):
//  - LDS table is float4 sc4[j] = (c[j],c[j+1],c[j+2],c[j+3]) -> each point's
//    4-tap gather is ONE aligned ds_read_b128 instead of 4 scalar ds_read_b32
//    (4x fewer LDS issues; random-j bank conflicts collapse into the 8
//    bank-cycle minimum a wave64 b128 read needs anyway).
//  - 2 float4 per thread (grid 2048 blocks, 8 blocks/CU = full occupancy):
//    halves table-build overhead, 2 independent chains/lane for latency hiding.
//  - weight math in symmetric FMA form: w1 = t^3/2 - t^2 + 2/3, w2 = w1(1-t);
//    clamp in float domain (no int round-trip).

__global__ __launch_bounds__(256) void bspline_kernel(
    const float* __restrict__ x,
    const float* __restrict__ coeffs,
    float* __restrict__ out,
    int n4)
{
    __shared__ float4 sc4[64];
    const int tid = threadIdx.x;
    if (tid < 63) {
        sc4[tid] = make_float4(coeffs[tid], coeffs[tid + 1],
                               coeffs[tid + 2], coeffs[tid + 3]);
    }
    __syncthreads();

    const float4* __restrict__ x4 = (const float4*)x;
    float4* __restrict__ out4 = (float4*)out;

    const float H_INV = 31.5f;           // (KNOTS-1)/2
    const float SIXTH = 1.0f / 6.0f;
    const float TWO3  = 2.0f / 3.0f;

    const int base = blockIdx.x * (256 * 2) + tid;

#pragma unroll
    for (int r = 0; r < 2; ++r) {
        const int idx = base + r * 256;
        if (idx < n4) {
            float4 xv = x4[idx];
            float xs[4] = {xv.x, xv.y, xv.z, xv.w};
            float os[4];
#pragma unroll
            for (int k = 0; k < 4; ++k) {
                float u  = fmaf(xs[k], H_INV, H_INV);
                float fj = floorf(u);
                fj = fminf(fmaxf(fj, 0.0f), 62.0f);
                float t  = u - fj;
                int   j  = (int)fj;
                float s  = 1.0f - t;
                float t2 = t * t;
                float s2 = s * s;
                float w0 = s * s2 * SIXTH;                      // s^3/6
                float w3 = t * t2 * SIXTH;                      // t^3/6
                float w1 = fmaf(t2, fmaf(t, 0.5f, -1.0f), TWO3); // t^3/2 - t^2 + 2/3
                float w2 = fmaf(s2, fmaf(s, 0.5f, -1.0f), TWO3); // symmetric
                float4 c = sc4[j];                               // ds_read_b128
                os[k] = fmaf(w0, c.x, fmaf(w1, c.y, fmaf(w2, c.z, w3 * c.w)));
            }
            out4[idx] = make_float4(os[0], os[1], os[2], os[3]);
        }
    }
}

extern "C" void kernel_launch(void* const* d_in, const int* in_sizes, int n_in,
                              void* d_out, int out_size, void* d_ws, size_t ws_size,
                              hipStream_t stream) {
    const float* x      = (const float*)d_in[0];
    const float* coeffs = (const float*)d_in[1];
    // d_in[2] is the grid buffer; it is uniform so we use the analytic h.
    float* out = (float*)d_out;

    int n  = in_sizes[0];          // 4194304, multiple of 4
    int n4 = n >> 2;               // 1048576 float4 elements
    int block = 256;
    int grid  = (n4 + block * 2 - 1) / (block * 2);  // 2048 blocks, 2 float4/thread

    bspline_kernel<<<grid, block, 0, stream>>>(x, coeffs, out, n4);
}